// Round 10
// baseline (125.166 us; speedup 1.0000x reference)
//
#include <hip/hip_runtime.h>

// VQ-VAE eval forward, MFMA bf16x3-split path (fp32-faithful distances).
// B=64, D=64, H=32, W=32 -> N=65536 queries dim 64; K=1024 codes.
// dist(q,c) = ||e_c||^2 - 2 <x_q, e_c>  (||x||^2 dropped: per-query constant,
// fp32 add of a constant is monotonic -> argmin preserved incl. tie order).
// <x,e> via 6 bf16 MFMA products: x=xh+xm+xl exactly; keep hh,hm,mh,mm,hl,lh.
//
// R10 = R9 (60.1us vq_main; best) + two scheduling-only changes:
//  (a) stage_write hoisted mid-tile (between cs1 and cs2): its VALU+ds_writes
//      interleave with cs2/cs3's 48 MFMAs instead of serializing as a ~400cy
//      tail before the barrier. Writes target the INACTIVE buffer, addresses
//      tid-disjoint, barrier skew <=1 tile -> race-free.
//  (b) s_setprio(1) around MFMA clusters (T5): two staggered blocks/CU give
//      wave role diversity; prefer the MFMA-issuing wave.
// No arithmetic change anywhere -> bit-identical outputs vs R9.
// Attribution bank: fused finalize +45us (R1/R2/R4/R5); bulk d_ws hot-loop
// traffic +23us (R7); 1 vs 2 blocks/CU only ±5us (R4vR5); 32x32 shape +3.7us
// (R8); cvt_pk split -16us (R9). Fixed harness overhead ~64us.

#define DIMS 64
#define K_CODES 1024
#define N_QUERIES 65536
#define HW 1024
#define TOTAL_ELEMS 4194304
#define PLANE 4096  // shorts per plane in a code-tile buffer: 8 octets * 64 slots * 8

typedef __attribute__((ext_vector_type(8))) short v8s;   // 8 bf16 = 4 VGPR (A/B frag)
typedef __attribute__((ext_vector_type(4))) float f32x4; // C/D frag

// HW packed fp32->bf16 RNE convert: returns [bf16(hi)<<16 | bf16(lo)],
// i.e. shorts {lo, hi} in memory order. Bit-identical to manual RNE.
__device__ inline unsigned cvtpk(float lo, float hi) {
    unsigned r;
    asm("v_cvt_pk_bf16_f32 %0, %1, %2" : "=v"(r) : "v"(lo), "v"(hi));
    return r;
}
__device__ inline float lo2f(unsigned u) {  // bf16 in low half -> fp32
    union { unsigned u; float f; } v; v.u = u << 16; return v.f;
}
__device__ inline float hi2f(unsigned u) {  // bf16 in high half -> fp32
    union { unsigned u; float f; } v; v.u = u & 0xffff0000u; return v.f;
}

// ---------------- Kernel A: code norms + zero accumulators ----------------
__global__ void vq_prep(const float* __restrict__ emb, float* __restrict__ ws_norm,
                        int* __restrict__ ws_flags, float* __restrict__ ws_loss) {
    int k = blockIdx.x * 256 + threadIdx.x;  // 0..1023
    const float4* row = (const float4*)(emb + k * DIMS);
    float s = 0.f;
#pragma unroll
    for (int i = 0; i < 16; ++i) {
        float4 v = row[i];
        s += v.x * v.x + v.y * v.y + v.z * v.z + v.w * v.w;
    }
    ws_norm[k] = s;
    ws_flags[k] = 0;
    if (k == 0) *ws_loss = 0.f;
}

#define MFMA16(A_, B_, C_) __builtin_amdgcn_mfma_f32_16x16x32_bf16(A_, B_, C_, 0, 0, 0)

// ---------------- Kernel B: MFMA distances + argmin + gather + loss ----------------
// 512 blocks x 256 threads (4 waves), 2 blocks/CU. Block = 128 queries; wave =
// 32 queries (2 row-tiles of 16), each wave scans ALL 1024 codes in 16 tiles of 64.
__global__ __launch_bounds__(256, 2)
void vq_main(const float* __restrict__ z_e, const float* __restrict__ emb,
             const float* __restrict__ ws_norm, int* __restrict__ ws_flags,
             float* __restrict__ ws_loss, float* __restrict__ out) {
    // Double-buffered code tile, frag-ready: [buf][plane p][octet o][slot][8 bf16]
    // slot = code ^ (o<<1)  (bank-conflict swizzle on code bits 1-3)
    __shared__ unsigned short ldsB[2][3 * PLANE];  // 48 KB
    __shared__ int   fIdx[128];
    __shared__ float wsum[4];

    const int tid  = threadIdx.x;
    const int lane = tid & 63;
    const int wid  = tid >> 6;
    const int qbase = blockIdx.x * 128;
    const int b    = qbase >> 10;          // batch index (uniform per block)
    const int hwb  = qbase & (HW - 1);

    const int col  = lane & 15;  // m (A) / n (B) within 16-tile
    const int qd   = lane >> 4;  // quad -> k-octet selector

    // ---- Build A fragments from global (coalesced), split into 3 bf16 planes ----
    // A[m=col][k=qd*8+j]; dims d = kc*32 + qd*8 + j. afr[rt][kc][plane]
    v8s afr[2][2][3];
    {
        const float* zb = z_e + b * (DIMS * HW);
#pragma unroll
        for (int rt = 0; rt < 2; ++rt) {
            int hwq = hwb + wid * 32 + rt * 16 + col;
#pragma unroll
            for (int kc = 0; kc < 2; ++kc) {
                int dbase = kc * 32 + qd * 8;
                float x[8];
#pragma unroll
                for (int j = 0; j < 8; ++j) x[j] = zb[(dbase + j) * HW + hwq];
                unsigned* ah = (unsigned*)&afr[rt][kc][0];
                unsigned* am = (unsigned*)&afr[rt][kc][1];
                unsigned* al = (unsigned*)&afr[rt][kc][2];
#pragma unroll
                for (int j2 = 0; j2 < 4; ++j2) {
                    float xa = x[2 * j2], xb = x[2 * j2 + 1];
                    unsigned uh = cvtpk(xa, xb);
                    float ra = xa - lo2f(uh), rb = xb - hi2f(uh);
                    unsigned um = cvtpk(ra, rb);
                    float sa = ra - lo2f(um), sb = rb - hi2f(um);
                    ah[j2] = uh; am[j2] = um; al[j2] = cvtpk(sa, sb);
                }
            }
        }
    }

    float bestv[2][4];
    int   besti[2][4];
#pragma unroll
    for (int rt = 0; rt < 2; ++rt)
#pragma unroll
        for (int r = 0; r < 4; ++r) { bestv[rt][r] = 3.4e38f; besti[rt][r] = 0; }

    float4 regs[4];  // staging pipeline registers (16 fp32 = one 64-code tile / 256 thr)

    // Stage tile t's 64x64 fp32 into regs (fully coalesced: tile is contiguous).
    auto stage_loads = [&](int t) {
        const float4* src = (const float4*)(emb + t * 64 * DIMS);
#pragma unroll
        for (int i = 0; i < 4; ++i) regs[i] = src[tid + 256 * i];
    };
    // Split via cvt_pk + scatter into frag-ready LDS layout, swizzled (8B writes).
    auto stage_write = [&](int bb) {
        unsigned short* dst = &ldsB[bb][0];
#pragma unroll
        for (int i = 0; i < 4; ++i) {
            int e    = (tid + 256 * i) * 4;  // flat element in tile
            int code = e >> 6;
            int d    = e & 63;               // 4-aligned
            int o    = d >> 3;
            int sub  = d & 7;                // 0 or 4
            float x0 = regs[i].x, x1 = regs[i].y, x2 = regs[i].z, x3 = regs[i].w;
            unsigned uh0 = cvtpk(x0, x1), uh1 = cvtpk(x2, x3);
            float r10 = x0 - lo2f(uh0), r11 = x1 - hi2f(uh0);
            float r12 = x2 - lo2f(uh1), r13 = x3 - hi2f(uh1);
            unsigned um0 = cvtpk(r10, r11), um1 = cvtpk(r12, r13);
            float r20 = r10 - lo2f(um0), r21 = r11 - hi2f(um0);
            float r22 = r12 - lo2f(um1), r23 = r13 - hi2f(um1);
            unsigned ul0 = cvtpk(r20, r21), ul1 = cvtpk(r22, r23);
            int base = (o * 64 + (code ^ (o << 1))) * 8 + sub;  // swizzled slot
            uint2 uh = {uh0, uh1}, um = {um0, um1}, ul = {ul0, ul1};
            *(uint2*)(dst + base)             = uh;
            *(uint2*)(dst + PLANE + base)     = um;
            *(uint2*)(dst + 2 * PLANE + base) = ul;
        }
    };

    stage_loads(0);
    stage_write(0);
    __syncthreads();

    for (int t = 0; t < 16; ++t) {
        const int cur = t & 1;
        if (t < 15) stage_loads(t + 1);
        const unsigned short* bufc = &ldsB[cur][0];

        auto csbody = [&](int cs) {
            float nrm = ws_norm[t * 64 + cs * 16 + col];
            // B-frags: B[n=col][k=qd*8+j], octet = kc*4+qd, swizzled slot.
            v8s bfr[2][3];
#pragma unroll
            for (int kc = 0; kc < 2; ++kc) {
                int oct  = kc * 4 + qd;
                int slot = (cs * 16 + col) ^ (oct << 1);
#pragma unroll
                for (int p = 0; p < 3; ++p)
                    bfr[kc][p] = *(const v8s*)(bufc + p * PLANE + (oct * 64 + slot) * 8);
            }
            f32x4 acc0 = {0.f, 0.f, 0.f, 0.f};
            f32x4 acc1 = {0.f, 0.f, 0.f, 0.f};
            __builtin_amdgcn_s_setprio(1);
#pragma unroll
            for (int kc = 0; kc < 2; ++kc) {
                acc0 = MFMA16(afr[0][kc][0], bfr[kc][0], acc0);  // hh
                acc1 = MFMA16(afr[1][kc][0], bfr[kc][0], acc1);
                acc0 = MFMA16(afr[0][kc][0], bfr[kc][1], acc0);  // hm
                acc1 = MFMA16(afr[1][kc][0], bfr[kc][1], acc1);
                acc0 = MFMA16(afr[0][kc][1], bfr[kc][0], acc0);  // mh
                acc1 = MFMA16(afr[1][kc][1], bfr[kc][0], acc1);
                acc0 = MFMA16(afr[0][kc][1], bfr[kc][1], acc0);  // mm
                acc1 = MFMA16(afr[1][kc][1], bfr[kc][1], acc1);
                acc0 = MFMA16(afr[0][kc][0], bfr[kc][2], acc0);  // hl
                acc1 = MFMA16(afr[1][kc][0], bfr[kc][2], acc1);
                acc0 = MFMA16(afr[0][kc][2], bfr[kc][0], acc0);  // lh
                acc1 = MFMA16(afr[1][kc][2], bfr[kc][0], acc1);
            }
            __builtin_amdgcn_s_setprio(0);
            int cbase = t * 64 + cs * 16 + col;
#pragma unroll
            for (int r = 0; r < 4; ++r) {
                float d0 = fmaf(-2.f, acc0[r], nrm);
                if (d0 < bestv[0][r]) { bestv[0][r] = d0; besti[0][r] = cbase; }
                float d1 = fmaf(-2.f, acc1[r], nrm);
                if (d1 < bestv[1][r]) { bestv[1][r] = d1; besti[1][r] = cbase; }
            }
        };

        csbody(0);
        csbody(1);
        // Mid-tile stage: writes target the INACTIVE buffer (1-cur); the barrier
        // at the end of tile t-1 guarantees no wave still reads it; peer writes
        // are tid-disjoint. Interleaves stage VALU/ds_writes with cs2/cs3 MFMAs.
        if (t < 15) stage_write(1 - cur);
        csbody(2);
        csbody(3);
        __syncthreads();
    }

    // ---- Final argmin across the 16 columns held by this quad's lanes ----
    // C/D: row = qd*4 + r, col = lane&15. Lanes of a quad share rows, span cols.
#pragma unroll
    for (int rt = 0; rt < 2; ++rt)
#pragma unroll
    for (int r = 0; r < 4; ++r) {
        float v = bestv[rt][r];
        int   idx = besti[rt][r];
#pragma unroll
        for (int m = 8; m >= 1; m >>= 1) {
            float ov = __shfl_xor(v, m, 64);
            int   oi = __shfl_xor(idx, m, 64);
            if (ov < v || (ov == v && oi < idx)) { v = ov; idx = oi; }
        }
        if (col == 0) {
            int q = wid * 32 + rt * 16 + qd * 4 + r;  // within block
            fIdx[q] = idx;
            out[TOTAL_ELEMS + 1 + qbase + q] = (float)idx;
            ws_flags[idx] = 1;  // benign race
        }
    }
    __syncthreads();

    // ---- Gather z_q, write coalesced, accumulate mse partial ----
    const int q  = tid & 127;
    const int dh = tid >> 7;  // even/odd dims
    const int n  = qbase + q;
    const int bb = n >> 10;
    const int hw = n & (HW - 1);
    const int myIdx = fIdx[q];
    const float* erow = emb + myIdx * DIMS;
    float lsum = 0.f;
#pragma unroll
    for (int it = 0; it < 32; ++it) {
        int d = it * 2 + dh;
        float v = erow[d];                         // random row, L2/L3-resident
        int   o = bb * (DIMS * HW) + d * HW + hw;  // consecutive q -> coalesced
        float ze = z_e[o];
        out[o] = v;
        float df = ze - v;
        lsum = fmaf(df, df, lsum);
    }
#pragma unroll
    for (int off = 32; off > 0; off >>= 1) lsum += __shfl_down(lsum, off, 64);
    if (lane == 0) wsum[wid] = lsum;
    __syncthreads();
    if (tid == 0) atomicAdd(ws_loss, wsum[0] + wsum[1] + wsum[2] + wsum[3]);
}

// ---------------- Kernel C: finalize loss + usage ----------------
__global__ void vq_final(const int* __restrict__ flags, const float* __restrict__ loss,
                         float* __restrict__ out) {
    __shared__ int cnt[256];
    int tid = threadIdx.x;
    int c = flags[tid] + flags[tid + 256] + flags[tid + 512] + flags[tid + 768];
    cnt[tid] = c;
    __syncthreads();
    for (int s = 128; s > 0; s >>= 1) {
        if (tid < s) cnt[tid] += cnt[tid + s];
        __syncthreads();
    }
    if (tid == 0) {
        out[TOTAL_ELEMS] = *loss / (float)TOTAL_ELEMS;
        out[TOTAL_ELEMS + 1 + N_QUERIES] = (float)cnt[0] / (float)K_CODES;
    }
}

extern "C" void kernel_launch(void* const* d_in, const int* in_sizes, int n_in,
                              void* d_out, int out_size, void* d_ws, size_t ws_size,
                              hipStream_t stream) {
    const float* z_e = (const float*)d_in[0];
    const float* emb = (const float*)d_in[1];
    float* out = (float*)d_out;
    float* ws_norm  = (float*)d_ws;
    int*   ws_flags = (int*)((char*)d_ws + 4096);
    float* ws_loss  = (float*)((char*)d_ws + 8192);

    vq_prep<<<4, 256, 0, stream>>>(emb, ws_norm, ws_flags, ws_loss);
    vq_main<<<512, 256, 0, stream>>>(z_e, emb, ws_norm, ws_flags, ws_loss, out);
    vq_final<<<1, 256, 0, stream>>>(ws_flags, ws_loss, out);
}

// Round 11
// 124.405 us; speedup vs baseline: 1.0061x; 1.0061x over previous
//
#include <hip/hip_runtime.h>

// VQ-VAE eval forward, MFMA bf16x3-split path (fp32-faithful distances).
// B=64, D=64, H=32, W=32 -> N=65536 queries dim 64; K=1024 codes.
// dist(q,c) = ||e_c||^2 - 2 <x_q, e_c>  (||x||^2 dropped: per-query constant,
// fp32 add of a constant is monotonic -> argmin preserved incl. tie order).
// <x,e> via 6 bf16 MFMA products: x=xh+xm+xl exactly; keep hh,hm,mh,mm,hl,lh.
//
// R11 = R10 (60.5us ~= R9 60.1; hoist+setprio neutral, kept harmless) +
// cs-level software pipeline: B-fragments double-buffered in registers
// (bE/bO); cs+1's 6 ds_read_b128 + norm issue BEFORE cs's 24-MFMA cluster,
// hiding the ~120-190cy LDS read latency under ~230cy of MFMA for 3 of the
// 4 cs-steps per tile (cs0 after the barrier stays exposed - unavoidable).
// No arithmetic change -> bit-identical outputs vs R9/R10.
// Attribution bank: fused finalize +45us (R1/R2/R4/R5); bulk d_ws hot-loop
// traffic +23us (R7); 32x32 shape +3.7us (R8); cvt_pk split -16us (R9);
// mid-tile hoist + setprio neutral (R10). Occupancy pinned at 8 waves/CU by
// the 2048-wave geometry; MFMA ~17% of peak, HBM ~5% -> latency-bound.

#define DIMS 64
#define K_CODES 1024
#define N_QUERIES 65536
#define HW 1024
#define TOTAL_ELEMS 4194304
#define PLANE 4096  // shorts per plane in a code-tile buffer: 8 octets * 64 slots * 8

typedef __attribute__((ext_vector_type(8))) short v8s;   // 8 bf16 = 4 VGPR (A/B frag)
typedef __attribute__((ext_vector_type(4))) float f32x4; // C/D frag

// HW packed fp32->bf16 RNE convert: returns [bf16(hi)<<16 | bf16(lo)],
// i.e. shorts {lo, hi} in memory order. Bit-identical to manual RNE.
__device__ inline unsigned cvtpk(float lo, float hi) {
    unsigned r;
    asm("v_cvt_pk_bf16_f32 %0, %1, %2" : "=v"(r) : "v"(lo), "v"(hi));
    return r;
}
__device__ inline float lo2f(unsigned u) {  // bf16 in low half -> fp32
    union { unsigned u; float f; } v; v.u = u << 16; return v.f;
}
__device__ inline float hi2f(unsigned u) {  // bf16 in high half -> fp32
    union { unsigned u; float f; } v; v.u = u & 0xffff0000u; return v.f;
}

// ---------------- Kernel A: code norms + zero accumulators ----------------
__global__ void vq_prep(const float* __restrict__ emb, float* __restrict__ ws_norm,
                        int* __restrict__ ws_flags, float* __restrict__ ws_loss) {
    int k = blockIdx.x * 256 + threadIdx.x;  // 0..1023
    const float4* row = (const float4*)(emb + k * DIMS);
    float s = 0.f;
#pragma unroll
    for (int i = 0; i < 16; ++i) {
        float4 v = row[i];
        s += v.x * v.x + v.y * v.y + v.z * v.z + v.w * v.w;
    }
    ws_norm[k] = s;
    ws_flags[k] = 0;
    if (k == 0) *ws_loss = 0.f;
}

#define MFMA16(A_, B_, C_) __builtin_amdgcn_mfma_f32_16x16x32_bf16(A_, B_, C_, 0, 0, 0)

// ---------------- Kernel B: MFMA distances + argmin + gather + loss ----------------
// 512 blocks x 256 threads (4 waves), 2 blocks/CU. Block = 128 queries; wave =
// 32 queries (2 row-tiles of 16), each wave scans ALL 1024 codes in 16 tiles of 64.
__global__ __launch_bounds__(256, 2)
void vq_main(const float* __restrict__ z_e, const float* __restrict__ emb,
             const float* __restrict__ ws_norm, int* __restrict__ ws_flags,
             float* __restrict__ ws_loss, float* __restrict__ out) {
    // Double-buffered code tile, frag-ready: [buf][plane p][octet o][slot][8 bf16]
    // slot = code ^ (o<<1)  (bank-conflict swizzle on code bits 1-3)
    __shared__ unsigned short ldsB[2][3 * PLANE];  // 48 KB
    __shared__ int   fIdx[128];
    __shared__ float wsum[4];

    const int tid  = threadIdx.x;
    const int lane = tid & 63;
    const int wid  = tid >> 6;
    const int qbase = blockIdx.x * 128;
    const int b    = qbase >> 10;          // batch index (uniform per block)
    const int hwb  = qbase & (HW - 1);

    const int col  = lane & 15;  // m (A) / n (B) within 16-tile
    const int qd   = lane >> 4;  // quad -> k-octet selector

    // ---- Build A fragments from global (coalesced), split into 3 bf16 planes ----
    // A[m=col][k=qd*8+j]; dims d = kc*32 + qd*8 + j. afr[rt][kc][plane]
    v8s afr[2][2][3];
    {
        const float* zb = z_e + b * (DIMS * HW);
#pragma unroll
        for (int rt = 0; rt < 2; ++rt) {
            int hwq = hwb + wid * 32 + rt * 16 + col;
#pragma unroll
            for (int kc = 0; kc < 2; ++kc) {
                int dbase = kc * 32 + qd * 8;
                float x[8];
#pragma unroll
                for (int j = 0; j < 8; ++j) x[j] = zb[(dbase + j) * HW + hwq];
                unsigned* ah = (unsigned*)&afr[rt][kc][0];
                unsigned* am = (unsigned*)&afr[rt][kc][1];
                unsigned* al = (unsigned*)&afr[rt][kc][2];
#pragma unroll
                for (int j2 = 0; j2 < 4; ++j2) {
                    float xa = x[2 * j2], xb = x[2 * j2 + 1];
                    unsigned uh = cvtpk(xa, xb);
                    float ra = xa - lo2f(uh), rb = xb - hi2f(uh);
                    unsigned um = cvtpk(ra, rb);
                    float sa = ra - lo2f(um), sb = rb - hi2f(um);
                    ah[j2] = uh; am[j2] = um; al[j2] = cvtpk(sa, sb);
                }
            }
        }
    }

    float bestv[2][4];
    int   besti[2][4];
#pragma unroll
    for (int rt = 0; rt < 2; ++rt)
#pragma unroll
        for (int r = 0; r < 4; ++r) { bestv[rt][r] = 3.4e38f; besti[rt][r] = 0; }

    float4 regs[4];  // staging pipeline registers (16 fp32 = one 64-code tile / 256 thr)

    // Stage tile t's 64x64 fp32 into regs (fully coalesced: tile is contiguous).
    auto stage_loads = [&](int t) {
        const float4* src = (const float4*)(emb + t * 64 * DIMS);
#pragma unroll
        for (int i = 0; i < 4; ++i) regs[i] = src[tid + 256 * i];
    };
    // Split via cvt_pk + scatter into frag-ready LDS layout, swizzled (8B writes).
    auto stage_write = [&](int bb) {
        unsigned short* dst = &ldsB[bb][0];
#pragma unroll
        for (int i = 0; i < 4; ++i) {
            int e    = (tid + 256 * i) * 4;  // flat element in tile
            int code = e >> 6;
            int d    = e & 63;               // 4-aligned
            int o    = d >> 3;
            int sub  = d & 7;                // 0 or 4
            float x0 = regs[i].x, x1 = regs[i].y, x2 = regs[i].z, x3 = regs[i].w;
            unsigned uh0 = cvtpk(x0, x1), uh1 = cvtpk(x2, x3);
            float r10 = x0 - lo2f(uh0), r11 = x1 - hi2f(uh0);
            float r12 = x2 - lo2f(uh1), r13 = x3 - hi2f(uh1);
            unsigned um0 = cvtpk(r10, r11), um1 = cvtpk(r12, r13);
            float r20 = r10 - lo2f(um0), r21 = r11 - hi2f(um0);
            float r22 = r12 - lo2f(um1), r23 = r13 - hi2f(um1);
            unsigned ul0 = cvtpk(r20, r21), ul1 = cvtpk(r22, r23);
            int base = (o * 64 + (code ^ (o << 1))) * 8 + sub;  // swizzled slot
            uint2 uh = {uh0, uh1}, um = {um0, um1}, ul = {ul0, ul1};
            *(uint2*)(dst + base)             = uh;
            *(uint2*)(dst + PLANE + base)     = um;
            *(uint2*)(dst + 2 * PLANE + base) = ul;
        }
    };

    stage_loads(0);
    stage_write(0);
    __syncthreads();

    for (int t = 0; t < 16; ++t) {
        const int cur = t & 1;
        if (t < 15) stage_loads(t + 1);
        const unsigned short* bufc = &ldsB[cur][0];

        // B-fragments double-buffered in registers: cs+1's reads issue before
        // cs's MFMA cluster -> LDS latency hidden under 24 MFMAs (3 of 4 cs).
        v8s bE[2][3], bO[2][3];
        float nE, nO;

        auto loadB = [&](int cs, v8s (&bf)[2][3]) {
#pragma unroll
            for (int kc = 0; kc < 2; ++kc) {
                int oct  = kc * 4 + qd;
                int slot = (cs * 16 + col) ^ (oct << 1);
#pragma unroll
                for (int p = 0; p < 3; ++p)
                    bf[kc][p] = *(const v8s*)(bufc + p * PLANE + (oct * 64 + slot) * 8);
            }
        };
        auto mfmaB = [&](const v8s (&bf)[2][3], float nrm, int cbase) {
            f32x4 acc0 = {0.f, 0.f, 0.f, 0.f};
            f32x4 acc1 = {0.f, 0.f, 0.f, 0.f};
            __builtin_amdgcn_s_setprio(1);
#pragma unroll
            for (int kc = 0; kc < 2; ++kc) {
                acc0 = MFMA16(afr[0][kc][0], bf[kc][0], acc0);  // hh
                acc1 = MFMA16(afr[1][kc][0], bf[kc][0], acc1);
                acc0 = MFMA16(afr[0][kc][0], bf[kc][1], acc0);  // hm
                acc1 = MFMA16(afr[1][kc][0], bf[kc][1], acc1);
                acc0 = MFMA16(afr[0][kc][1], bf[kc][0], acc0);  // mh
                acc1 = MFMA16(afr[1][kc][1], bf[kc][0], acc1);
                acc0 = MFMA16(afr[0][kc][1], bf[kc][1], acc0);  // mm
                acc1 = MFMA16(afr[1][kc][1], bf[kc][1], acc1);
                acc0 = MFMA16(afr[0][kc][0], bf[kc][2], acc0);  // hl
                acc1 = MFMA16(afr[1][kc][0], bf[kc][2], acc1);
                acc0 = MFMA16(afr[0][kc][2], bf[kc][0], acc0);  // lh
                acc1 = MFMA16(afr[1][kc][2], bf[kc][0], acc1);
            }
            __builtin_amdgcn_s_setprio(0);
#pragma unroll
            for (int r = 0; r < 4; ++r) {
                float d0 = fmaf(-2.f, acc0[r], nrm);
                if (d0 < bestv[0][r]) { bestv[0][r] = d0; besti[0][r] = cbase; }
                float d1 = fmaf(-2.f, acc1[r], nrm);
                if (d1 < bestv[1][r]) { bestv[1][r] = d1; besti[1][r] = cbase; }
            }
        };

        loadB(0, bE); nE = ws_norm[t * 64 + col];
        loadB(1, bO); nO = ws_norm[t * 64 + 16 + col];
        mfmaB(bE, nE, t * 64 + col);                 // cs0 (cs1 reads in flight)
        loadB(2, bE); nE = ws_norm[t * 64 + 32 + col];
        mfmaB(bO, nO, t * 64 + 16 + col);            // cs1 (cs2 reads in flight)
        // Mid-tile stage: writes target the INACTIVE buffer (1-cur); the barrier
        // at the end of tile t-1 guarantees no wave still reads it; peer writes
        // are tid-disjoint. Interleaves stage VALU/ds_writes with cs2/cs3 MFMAs.
        if (t < 15) stage_write(1 - cur);
        loadB(3, bO); nO = ws_norm[t * 64 + 48 + col];
        mfmaB(bE, nE, t * 64 + 32 + col);            // cs2 (cs3 reads in flight)
        mfmaB(bO, nO, t * 64 + 48 + col);            // cs3
        __syncthreads();
    }

    // ---- Final argmin across the 16 columns held by this quad's lanes ----
    // C/D: row = qd*4 + r, col = lane&15. Lanes of a quad share rows, span cols.
#pragma unroll
    for (int rt = 0; rt < 2; ++rt)
#pragma unroll
    for (int r = 0; r < 4; ++r) {
        float v = bestv[rt][r];
        int   idx = besti[rt][r];
#pragma unroll
        for (int m = 8; m >= 1; m >>= 1) {
            float ov = __shfl_xor(v, m, 64);
            int   oi = __shfl_xor(idx, m, 64);
            if (ov < v || (ov == v && oi < idx)) { v = ov; idx = oi; }
        }
        if (col == 0) {
            int q = wid * 32 + rt * 16 + qd * 4 + r;  // within block
            fIdx[q] = idx;
            out[TOTAL_ELEMS + 1 + qbase + q] = (float)idx;
            ws_flags[idx] = 1;  // benign race
        }
    }
    __syncthreads();

    // ---- Gather z_q, write coalesced, accumulate mse partial ----
    const int q  = tid & 127;
    const int dh = tid >> 7;  // even/odd dims
    const int n  = qbase + q;
    const int bb = n >> 10;
    const int hw = n & (HW - 1);
    const int myIdx = fIdx[q];
    const float* erow = emb + myIdx * DIMS;
    float lsum = 0.f;
#pragma unroll
    for (int it = 0; it < 32; ++it) {
        int d = it * 2 + dh;
        float v = erow[d];                         // random row, L2/L3-resident
        int   o = bb * (DIMS * HW) + d * HW + hw;  // consecutive q -> coalesced
        float ze = z_e[o];
        out[o] = v;
        float df = ze - v;
        lsum = fmaf(df, df, lsum);
    }
#pragma unroll
    for (int off = 32; off > 0; off >>= 1) lsum += __shfl_down(lsum, off, 64);
    if (lane == 0) wsum[wid] = lsum;
    __syncthreads();
    if (tid == 0) atomicAdd(ws_loss, wsum[0] + wsum[1] + wsum[2] + wsum[3]);
}

// ---------------- Kernel C: finalize loss + usage ----------------
__global__ void vq_final(const int* __restrict__ flags, const float* __restrict__ loss,
                         float* __restrict__ out) {
    __shared__ int cnt[256];
    int tid = threadIdx.x;
    int c = flags[tid] + flags[tid + 256] + flags[tid + 512] + flags[tid + 768];
    cnt[tid] = c;
    __syncthreads();
    for (int s = 128; s > 0; s >>= 1) {
        if (tid < s) cnt[tid] += cnt[tid + s];
        __syncthreads();
    }
    if (tid == 0) {
        out[TOTAL_ELEMS] = *loss / (float)TOTAL_ELEMS;
        out[TOTAL_ELEMS + 1 + N_QUERIES] = (float)cnt[0] / (float)K_CODES;
    }
}

extern "C" void kernel_launch(void* const* d_in, const int* in_sizes, int n_in,
                              void* d_out, int out_size, void* d_ws, size_t ws_size,
                              hipStream_t stream) {
    const float* z_e = (const float*)d_in[0];
    const float* emb = (const float*)d_in[1];
    float* out = (float*)d_out;
    float* ws_norm  = (float*)d_ws;
    int*   ws_flags = (int*)((char*)d_ws + 4096);
    float* ws_loss  = (float*)((char*)d_ws + 8192);

    vq_prep<<<4, 256, 0, stream>>>(emb, ws_norm, ws_flags, ws_loss);
    vq_main<<<512, 256, 0, stream>>>(z_e, emb, ws_norm, ws_flags, ws_loss, out);
    vq_final<<<1, 256, 0, stream>>>(ws_flags, ws_loss, out);
}